// Round 10
// baseline (382.690 us; speedup 1.0000x reference)
//
#include <hip/hip_runtime.h>
#include <hip/hip_bf16.h>

#define N_NODES 20000
#define N_EDGES 320000
#define HID 256

typedef __attribute__((ext_vector_type(8))) short bf16x8;   // 8 bf16 = 4 VGPRs (MFMA A/B frag)
typedef __attribute__((ext_vector_type(4))) float f32x4;    // MFMA C/D frag
typedef __attribute__((ext_vector_type(8))) unsigned short us8;  // 16B row chunk

__device__ __forceinline__ float bf2f(ushort u) {
  union { unsigned int i; float f; } v; v.i = ((unsigned int)u) << 16; return v.f;
}
__device__ __forceinline__ ushort f2bf(float f) {
  union { float f; unsigned int i; } v; v.f = f;
  unsigned int r = v.i + 0x7FFFu + ((v.i >> 16) & 1u);   // RNE
  return (ushort)(r >> 16);
}

// ---------------------------------------------------------------------------
// init (zero accumulated state) + runtime dtype detection fused.
// flags[0]=1 -> x/weights fp32 (else bf16). flags[1]=1 -> edges int64.
// ---------------------------------------------------------------------------
__global__ void init_detect_kernel(int* cnt0, int* cnt1, float* t0, float* t1,
                                   const void* x1, const void* ei1, int* flags) {
  if (blockIdx.x == gridDim.x - 1) {
    __shared__ int cnt_wild, cnt_oddnz;
    if (threadIdx.x == 0) { cnt_wild = 0; cnt_oddnz = 0; }
    __syncthreads();
    const ushort* xu = (const ushort*)x1;
    int wild = 0;
#pragma unroll
    for (int k = 0; k < 4; k++) {
      ushort u = xu[threadIdx.x * 4 + k];
      int ex = (u >> 7) & 0xFF;
      if (ex >= 0x90) wild++;
    }
    if (wild) atomicAdd(&cnt_wild, wild);
    const int* ii = (const int*)ei1;
    if (ii[threadIdx.x * 2 + 1] != 0) atomicAdd(&cnt_oddnz, 1);
    __syncthreads();
    if (threadIdx.x == 0) {
      flags[0] = (cnt_wild > 64) ? 1 : 0;
      flags[1] = (cnt_oddnz < 8) ? 1 : 0;
    }
    return;
  }
  int i = blockIdx.x * blockDim.x + threadIdx.x;
  if (i < N_NODES) { cnt0[i] = 0; cnt1[i] = 0; t0[i] = 0.f; t1[i] = 0.f; }
}

// Canonicalize edge_index -> int32 AND fused dst-histogram with rank capture
// (measured r2/r3: 640K device atomics ~= 40 us; replication is worse, r4).
__global__ void cvt_ei_count_kernel(const void* e0, const void* e1,
                                    int* o0, int* o1,
                                    int* cnt0, int* cnt1,
                                    int* rank0, int* rank1, const int* flags) {
  int b = blockIdx.y;
  const void* e = b ? e1 : e0;
  int* o = b ? o1 : o0;
  int* cnt = b ? cnt1 : cnt0;
  int* rank = b ? rank1 : rank0;
  int i = blockIdx.x * 256 + threadIdx.x;
  if (i >= 2 * N_EDGES) return;
  int v = flags[1] ? (int)((const long long*)e)[i] : ((const int*)e)[i];
  o[i] = v;
  if (i >= N_EDGES) rank[i - N_EDGES] = atomicAdd(&cnt[v], 1);
}

// Canonicalize all weights/biases -> one packed bf16 buffer.
// W1/W2 stored TRANSPOSED (Wt[n*256+k]) -- kills gemm B-stage LDS conflicts (r5->r6).
// Layout: W1t[0] W2t[65536] W3[131072] Wl[196608] b1[197888] b2[198144]
//         b3[198400] bl[198656]; total 198661 elems.
__global__ void cvt_w_kernel(const void* W1, const void* W2, const void* W3, const void* Wl,
                             const void* b1, const void* b2, const void* b3, const void* bl,
                             ushort* out, const int* flags) {
  int i = blockIdx.x * 256 + threadIdx.x;
  if (i >= 198661) return;
  const void* src; int off; bool tr = false;
  if (i < 65536)       { src = W1; off = 0; tr = true; }
  else if (i < 131072) { src = W2; off = 65536; tr = true; }
  else if (i < 196608) { src = W3; off = 131072; }
  else if (i < 197888) { src = Wl; off = 196608; }
  else if (i < 198144) { src = b1; off = 197888; }
  else if (i < 198400) { src = b2; off = 198144; }
  else if (i < 198656) { src = b3; off = 198400; }
  else                 { src = bl; off = 198656; }
  int j = i - off;
  if (tr) j = (j & 255) * 256 + (j >> 8);   // read W[k][n] for out index (n,k)
  out[i] = flags[0] ? f2bf(((const float*)src)[j]) : ((const ushort*)src)[j];
}

// Exclusive scan -> CSR row_ptr, fused with dinv = rsqrt(cnt+1).
__global__ __launch_bounds__(1024) void scan_kernel(const int* cnt0, const int* cnt1,
                                                    int* rp0, int* rp1,
                                                    float* dinv0, float* dinv1) {
  const int* cnt = blockIdx.x ? cnt1 : cnt0;
  int* rp = blockIdx.x ? rp1 : rp0;
  float* dinv = blockIdx.x ? dinv1 : dinv0;
  __shared__ int sd[1024];
  int tid = threadIdx.x;
  int base = tid * 20;
  int pref[20];
  int run = 0;
#pragma unroll
  for (int k = 0; k < 20; k++) {
    int i = base + k;
    int c = (i < N_NODES) ? cnt[i] : 0;
    if (i < N_NODES) dinv[i] = rsqrtf((float)c + 1.0f);
    run += c;
    pref[k] = run;
  }
  sd[tid] = run;
  __syncthreads();
  for (int off = 1; off < 1024; off <<= 1) {
    int v = (tid >= off) ? sd[tid - off] : 0;
    __syncthreads();
    sd[tid] += v;
    __syncthreads();
  }
  int offset = sd[tid] - run;
  if (tid == 0) rp[0] = 0;
#pragma unroll
  for (int k = 0; k < 20; k++) {
    int i = base + k;
    if (i < N_NODES) rp[i + 1] = offset + pref[k];
  }
}

// Fill CSR using precomputed rank (no slot atomic). Edge record packed 4 B:
// low16 = src, high16 = bf16(coef). Plus t[src] += dinv[dst] (layer-3
// shortcut c_j = dinv_j*(t_j+dinv_j)). Atomic+scatter latency-bound (r9).
__global__ void fill_kernel(const int* ei0, const int* ei1,
                            const float* dinv0, const float* dinv1,
                            const int* rp0, const int* rp1,
                            const int* rank0, const int* rank1,
                            unsigned int* eg0, unsigned int* eg1,
                            float* t0, float* t1) {
  int e = blockIdx.x * blockDim.x + threadIdx.x;
  if (e >= N_EDGES) return;
  int b = blockIdx.y;
  const int* ei = b ? ei1 : ei0;
  const float* dinv = b ? dinv1 : dinv0;
  const int* rp = b ? rp1 : rp0;
  const int* rank = b ? rank1 : rank0;
  unsigned int* eg = b ? eg1 : eg0;
  float* t = b ? t1 : t0;
  int src = ei[e], dst = ei[N_EDGES + e];
  int slot = rp[dst] + rank[e];
  float dd = dinv[dst];
  eg[slot] = (unsigned int)src | ((unsigned int)f2bf(dinv[src] * dd) << 16);
  atomicAdd(&t[src], dd);
}

// C[M,256] = A[M,256] @ W[256,256], W TRANSPOSED (Wt[n][k]).
// r10: 128x64 tile, 4 waves each 32x64 (2 M x 4 N subtiles, 8 MFMA/k-step);
// half the blocks of r9 -> half the W restaging; LDS stride 42 ushorts
// (21 dwords, coprime to 32 banks) kills residual 2.88e6 conflicts (r9).
// maybe_f32: gemm1 reads raw x (runtime fp32/bf16 branch, wave-uniform) --
// cvt_x pass deleted.
__global__ __launch_bounds__(256) void gemm_kernel(
    const void* __restrict__ A0, const void* __restrict__ A1,
    const ushort* __restrict__ Wt,
    ushort* __restrict__ C0, ushort* __restrict__ C1,
    int maybe_f32, const int* __restrict__ flags) {
  const void* A = blockIdx.z ? A1 : A0;
  ushort* C = blockIdx.z ? C1 : C0;
  bool f32 = maybe_f32 && flags[0];
  int m0 = blockIdx.x * 128;
  int n0 = blockIdx.y * 64;
  __shared__ ushort As[128][42];  // stride 84B: 21 dwords, coprime w/ 32 banks
  __shared__ ushort Bs[64][42];
  int tid = threadIdx.x;
  int wave = tid >> 6, lane = tid & 63;
  int quad = lane >> 4, r16 = lane & 15;
  f32x4 acc[2][4];
#pragma unroll
  for (int m = 0; m < 2; m++)
#pragma unroll
    for (int n = 0; n < 4; n++) acc[m][n] = (f32x4){0.f, 0.f, 0.f, 0.f};
  int la_row = tid >> 1;          // 0..127
  int la_c0 = (tid & 1) * 16;     // 0 or 16
  int lb_n = tid >> 2;            // 0..63
  int lb_k = (tid & 3) * 8;       // 0,8,16,24
  for (int k0 = 0; k0 < 256; k0 += 32) {
    int gr = m0 + la_row;
    if (f32) {
      const float* Af = (const float*)A;
      float4 v0 = {0,0,0,0}, v1 = v0, v2 = v0, v3 = v0;
      if (gr < N_NODES) {
        const float* pA = Af + gr * 256 + k0 + la_c0;
        v0 = *(const float4*)pA;       v1 = *(const float4*)(pA + 4);
        v2 = *(const float4*)(pA + 8); v3 = *(const float4*)(pA + 12);
      }
      ushort* d = &As[la_row][la_c0];
      d[0] = f2bf(v0.x); d[1] = f2bf(v0.y); d[2]  = f2bf(v0.z); d[3]  = f2bf(v0.w);
      d[4] = f2bf(v1.x); d[5] = f2bf(v1.y); d[6]  = f2bf(v1.z); d[7]  = f2bf(v1.w);
      d[8] = f2bf(v2.x); d[9] = f2bf(v2.y); d[10] = f2bf(v2.z); d[11] = f2bf(v2.w);
      d[12] = f2bf(v3.x); d[13] = f2bf(v3.y); d[14] = f2bf(v3.z); d[15] = f2bf(v3.w);
    } else {
      const ushort* Ab = (const ushort*)A;
      int4 w0 = {0,0,0,0}, w1 = w0;
      if (gr < N_NODES) {
        const ushort* pA = Ab + gr * 256 + k0 + la_c0;
        w0 = *(const int4*)pA;
        w1 = *(const int4*)(pA + 8);
      }
      *(int4*)&As[la_row][la_c0] = w0;
      *(int4*)&As[la_row][la_c0 + 8] = w1;
    }
    *(int4*)&Bs[lb_n][lb_k] = *(const int4*)(Wt + (n0 + lb_n) * 256 + k0 + lb_k);
    __syncthreads();
    bf16x8 a0 = *(const bf16x8*)&As[wave * 32 + r16][quad * 8];
    bf16x8 a1 = *(const bf16x8*)&As[wave * 32 + 16 + r16][quad * 8];
    bf16x8 bb0 = *(const bf16x8*)&Bs[r16][quad * 8];
    bf16x8 bb1 = *(const bf16x8*)&Bs[16 + r16][quad * 8];
    bf16x8 bb2 = *(const bf16x8*)&Bs[32 + r16][quad * 8];
    bf16x8 bb3 = *(const bf16x8*)&Bs[48 + r16][quad * 8];
    acc[0][0] = __builtin_amdgcn_mfma_f32_16x16x32_bf16(a0, bb0, acc[0][0], 0, 0, 0);
    acc[0][1] = __builtin_amdgcn_mfma_f32_16x16x32_bf16(a0, bb1, acc[0][1], 0, 0, 0);
    acc[0][2] = __builtin_amdgcn_mfma_f32_16x16x32_bf16(a0, bb2, acc[0][2], 0, 0, 0);
    acc[0][3] = __builtin_amdgcn_mfma_f32_16x16x32_bf16(a0, bb3, acc[0][3], 0, 0, 0);
    acc[1][0] = __builtin_amdgcn_mfma_f32_16x16x32_bf16(a1, bb0, acc[1][0], 0, 0, 0);
    acc[1][1] = __builtin_amdgcn_mfma_f32_16x16x32_bf16(a1, bb1, acc[1][1], 0, 0, 0);
    acc[1][2] = __builtin_amdgcn_mfma_f32_16x16x32_bf16(a1, bb2, acc[1][2], 0, 0, 0);
    acc[1][3] = __builtin_amdgcn_mfma_f32_16x16x32_bf16(a1, bb3, acc[1][3], 0, 0, 0);
    __syncthreads();
  }
#pragma unroll
  for (int m = 0; m < 2; m++) {
    int grb = m0 + wave * 32 + m * 16 + quad * 4;
#pragma unroll
    for (int r = 0; r < 4; r++) {
      int gr = grb + r;
      if (gr < N_NODES) {
        ushort* cp = C + gr * 256 + n0 + r16;
        cp[0]  = f2bf(acc[m][0][r]);
        cp[16] = f2bf(acc[m][1][r]);
        cp[32] = f2bf(acc[m][2][r]);
        cp[48] = f2bf(acc[m][3][r]);
      }
    }
  }
}

// H[i] = relu( dinv_i^2*XW[i] + sum_e coef_e*XW[src_e] + bias ).
// Wave = 2 independent 32-lane halves, one node each; lane owns 8 features
// (full 256-col row per half); no cross-lane merge; x4 unroll + dual
// accumulators keeps 8 full rows (64 lines) in flight (r8 post-mortem:
// line-level MLP >> cache-slice residency for random gathers).
__global__ __launch_bounds__(256) void agg_kernel(
    const ushort* __restrict__ XW0, const ushort* __restrict__ XW1,
    const float* __restrict__ dinv0, const float* __restrict__ dinv1,
    const int* __restrict__ rp0, const int* __restrict__ rp1,
    const unsigned int* __restrict__ eg0, const unsigned int* __restrict__ eg1,
    const ushort* __restrict__ bias,
    ushort* __restrict__ H0, ushort* __restrict__ H1) {
  int b = blockIdx.y;
  const ushort* XW = b ? XW1 : XW0;
  const float* dinv = b ? dinv1 : dinv0;
  const int* rp = b ? rp1 : rp0;
  const unsigned int* eg = b ? eg1 : eg0;
  ushort* H = b ? H1 : H0;
  int wave = threadIdx.x >> 6, lane = threadIdx.x & 63;
  int half = lane >> 5;
  int fl = (lane & 31) * 8;               // 8 features per lane = full row/half
  int i = blockIdx.x * 8 + wave * 2 + half;   // 2500*8 = 20000 exact
  float di = dinv[i];
  float selfw = di * di;
  us8 v = *(const us8*)(XW + i * 256 + fl);
  float acc[8], acc2[8];
#pragma unroll
  for (int k = 0; k < 8; k++) { acc[k] = selfw * bf2f(v[k]); acc2[k] = 0.f; }
  int e = rp[i], eend = rp[i + 1];
  for (; e + 4 <= eend; e += 4) {
    unsigned int p0 = eg[e], p1 = eg[e + 1], p2 = eg[e + 2], p3 = eg[e + 3];
    us8 r0 = *(const us8*)(XW + (p0 & 0xFFFFu) * 256 + fl);
    us8 r1 = *(const us8*)(XW + (p1 & 0xFFFFu) * 256 + fl);
    us8 r2 = *(const us8*)(XW + (p2 & 0xFFFFu) * 256 + fl);
    us8 r3 = *(const us8*)(XW + (p3 & 0xFFFFu) * 256 + fl);
    float w0 = bf2f((ushort)(p0 >> 16)), w1 = bf2f((ushort)(p1 >> 16));
    float w2 = bf2f((ushort)(p2 >> 16)), w3 = bf2f((ushort)(p3 >> 16));
#pragma unroll
    for (int k = 0; k < 8; k++) {
      acc[k]  += w0 * bf2f(r0[k]);
      acc2[k] += w1 * bf2f(r1[k]);
      acc[k]  += w2 * bf2f(r2[k]);
      acc2[k] += w3 * bf2f(r3[k]);
    }
  }
  for (; e < eend; e++) {
    unsigned int pp = eg[e];
    us8 r = *(const us8*)(XW + (pp & 0xFFFFu) * 256 + fl);
    float w = bf2f((ushort)(pp >> 16));
#pragma unroll
    for (int k = 0; k < 8; k++) acc[k] += w * bf2f(r[k]);
  }
  us8 bb = *(const us8*)(bias + fl);
  us8 o;
#pragma unroll
  for (int k = 0; k < 8; k++)
    o[k] = f2bf(fmaxf(acc[k] + acc2[k] + bf2f(bb[k]), 0.f));
  *(us8*)(H + i * 256 + fl) = o;
}

// Partial column sums: wave w of block handles rows j = (blk*4+w) + 256*k.
__global__ __launch_bounds__(256) void colsum_kernel(
    const ushort* __restrict__ H0, const ushort* __restrict__ H1,
    const float* __restrict__ dinv0, const float* __restrict__ dinv1,
    const float* __restrict__ t0, const float* __restrict__ t1,
    float* __restrict__ P) {
  int b = blockIdx.y;
  const ushort* H = b ? H1 : H0;
  const float* dinv = b ? dinv1 : dinv0;
  const float* t = b ? t1 : t0;
  int wave = threadIdx.x >> 6, lane = threadIdx.x & 63;
  int wid = blockIdx.x * 4 + wave;        // 0..255
  int f4 = lane * 4;
  float a0 = 0.f, a1 = 0.f, a2 = 0.f, a3 = 0.f;
  for (int j = wid; j < N_NODES; j += 256) {
    float dj = dinv[j];
    float c = dj * (t[j] + dj);
    ushort4 u = *(const ushort4*)(H + j * 256 + f4);
    a0 += c * bf2f(u.x); a1 += c * bf2f(u.y);
    a2 += c * bf2f(u.z); a3 += c * bf2f(u.w);
  }
  __shared__ float part[4][256];
  part[wave][f4 + 0] = a0; part[wave][f4 + 1] = a1;
  part[wave][f4 + 2] = a2; part[wave][f4 + 3] = a3;
  __syncthreads();
  int f = threadIdx.x;
  float ssum = part[0][f] + part[1][f] + part[2][f] + part[3][f];
  P[(b * 64 + blockIdx.x) * 256 + f] = ssum;
}

// s = reduce partials; pooled = ((s0+s1)@W3)/(2N)+b3 ; out = pooled@Wl + bl
__global__ __launch_bounds__(256) void final_kernel(
    const float* __restrict__ P,
    const ushort* __restrict__ W3, const ushort* __restrict__ b3,
    const ushort* __restrict__ Wl, const ushort* __restrict__ bl,
    void* __restrict__ out, const int* __restrict__ flags) {
  __shared__ float v[256];
  __shared__ float pooled[256];
  int t = threadIdx.x;
  float acc0 = 0.f, acc1 = 0.f;
  for (int b = 0; b < 64; b++) {
    acc0 += P[b * 256 + t];
    acc1 += P[(64 + b) * 256 + t];
  }
  v[t] = acc0 + acc1;
  __syncthreads();
  float acc = 0.f;
  for (int f = 0; f < 256; f++) acc += v[f] * bf2f(W3[f * 256 + t]);
  pooled[t] = acc * (1.0f / (2.0f * N_NODES)) + bf2f(b3[t]);
  __syncthreads();
  if (t < 5) {
    float o = bf2f(bl[t]);
    for (int h = 0; h < 256; h++) o += pooled[h] * bf2f(Wl[h * 5 + t]);
    if (flags[0]) ((float*)out)[t] = o;
    else ((ushort*)out)[t] = f2bf(o);
  }
}

extern "C" void kernel_launch(void* const* d_in, const int* in_sizes, int n_in,
                              void* d_out, int out_size, void* d_ws, size_t ws_size,
                              hipStream_t stream) {
  const void* x1 = d_in[0];
  const void* ei1 = d_in[1];
  const void* x2 = d_in[2];
  const void* ei2 = d_in[3];
  const void* W1 = d_in[4];
  const void* b1 = d_in[5];
  const void* W2 = d_in[6];
  const void* b2 = d_in[7];
  const void* W3 = d_in[8];
  const void* b3 = d_in[9];
  const void* Wl = d_in[10];
  const void* bl = d_in[11];

  char* p = (char*)d_ws;
  auto alloc = [&](size_t bytes) {
    char* r = p;
    p += (bytes + 255) & ~size_t(255);
    return r;
  };
  int* flags   = (int*)alloc(256);
  float* dinv0 = (float*)alloc(N_NODES * 4);
  float* dinv1 = (float*)alloc(N_NODES * 4);
  float* t0    = (float*)alloc(N_NODES * 4);
  float* t1    = (float*)alloc(N_NODES * 4);
  int* cnt0    = (int*)alloc(N_NODES * 4);
  int* cnt1    = (int*)alloc(N_NODES * 4);
  int* rp0     = (int*)alloc((N_NODES + 1) * 4);
  int* rp1     = (int*)alloc((N_NODES + 1) * 4);
  unsigned int* eg0 = (unsigned int*)alloc((size_t)N_EDGES * 4);
  unsigned int* eg1 = (unsigned int*)alloc((size_t)N_EDGES * 4);
  float* Pp    = (float*)alloc(2 * 64 * 256 * 4);
  ushort* wbuf = (ushort*)alloc(198661 * 2);
  ushort* xw0  = (ushort*)alloc((size_t)N_NODES * HID * 2);
  ushort* xw1  = (ushort*)alloc((size_t)N_NODES * HID * 2);
  ushort* h0   = (ushort*)alloc((size_t)N_NODES * HID * 2);
  ushort* h1   = (ushort*)alloc((size_t)N_NODES * HID * 2);
  // Lifetime aliasing: ei32+rank live only until fill_kernel; xw0 is first
  // written by gemm1 (after fill). 2*2.56 + 2*1.28 = 7.7MB <= 10.24MB.
  int* ei32_0 = (int*)xw0;
  int* ei32_1 = ei32_0 + 2 * N_EDGES;
  int* rank0  = ei32_1 + 2 * N_EDGES;
  int* rank1  = rank0 + N_EDGES;

  ushort* Wc1 = wbuf + 0;        // transposed
  ushort* Wc2 = wbuf + 65536;    // transposed
  ushort* Wc3 = wbuf + 131072;
  ushort* Wlc = wbuf + 196608;
  ushort* bc1 = wbuf + 197888;
  ushort* bc2 = wbuf + 198144;
  ushort* bc3 = wbuf + 198400;
  ushort* blc = wbuf + 198656;

  // --- init+detect fused, canonicalization, graph prep ---
  init_detect_kernel<<<(N_NODES + 255) / 256 + 1, 256, 0, stream>>>(
      cnt0, cnt1, t0, t1, x1, ei1, flags);
  cvt_ei_count_kernel<<<dim3((2 * N_EDGES + 255) / 256, 2), 256, 0, stream>>>(
      ei1, ei2, ei32_0, ei32_1, cnt0, cnt1, rank0, rank1, flags);
  cvt_w_kernel<<<(198661 + 255) / 256, 256, 0, stream>>>(
      W1, W2, W3, Wl, b1, b2, b3, bl, wbuf, flags);
  scan_kernel<<<2, 1024, 0, stream>>>(cnt0, cnt1, rp0, rp1, dinv0, dinv1);
  fill_kernel<<<dim3((N_EDGES + 255) / 256, 2), 256, 0, stream>>>(
      ei32_0, ei32_1, dinv0, dinv1, rp0, rp1, rank0, rank1, eg0, eg1, t0, t1);

  // Layer 1: xw = x @ W1 (raw x, runtime dtype) ; h = relu(agg(xw) + b1)
  gemm_kernel<<<dim3(157, 4, 2), 256, 0, stream>>>(x1, x2, Wc1, xw0, xw1, 1, flags);
  agg_kernel<<<dim3(2500, 2), 256, 0, stream>>>(
      xw0, xw1, dinv0, dinv1, rp0, rp1, eg0, eg1, bc1, h0, h1);

  // Layer 2: xw = h @ W2 ; h = relu(agg(xw) + b2)
  gemm_kernel<<<dim3(157, 4, 2), 256, 0, stream>>>(h0, h1, Wc2, xw0, xw1, 0, flags);
  agg_kernel<<<dim3(2500, 2), 256, 0, stream>>>(
      xw0, xw1, dinv0, dinv1, rp0, rp1, eg0, eg1, bc2, h0, h1);

  // Layer 3 + pool collapsed: s = sum_j c_j h2_j ; out = ((s0+s1)W3/(2N)+b3)@Wl+bl
  colsum_kernel<<<dim3(64, 2), 256, 0, stream>>>(h0, h1, dinv0, dinv1, t0, t1, Pp);
  final_kernel<<<1, 256, 0, stream>>>(Pp, Wc3, bc3, Wlc, blc, d_out, flags);
}

// Round 11
// 374.508 us; speedup vs baseline: 1.0218x; 1.0218x over previous
//
#include <hip/hip_runtime.h>
#include <hip/hip_bf16.h>

#define N_NODES 20000
#define N_EDGES 320000
#define HID 256
#define NQ 5000          // nodes per quarter (histogram privatization)
#define NCHUNK 8         // edge chunks per branch

typedef __attribute__((ext_vector_type(8))) short bf16x8;   // 8 bf16 = 4 VGPRs (MFMA A/B frag)
typedef __attribute__((ext_vector_type(4))) float f32x4;    // MFMA C/D frag
typedef __attribute__((ext_vector_type(8))) unsigned short us8;  // 16B row chunk

__device__ __forceinline__ float bf2f(ushort u) {
  union { unsigned int i; float f; } v; v.i = ((unsigned int)u) << 16; return v.f;
}
__device__ __forceinline__ ushort f2bf(float f) {
  union { float f; unsigned int i; } v; v.f = f;
  unsigned int r = v.i + 0x7FFFu + ((v.i >> 16) & 1u);   // RNE
  return (ushort)(r >> 16);
}

// ---------------------------------------------------------------------------
// init (zero cnt/t) + runtime dtype detection fused.
// flags[0]=1 -> x/weights fp32 (else bf16). flags[1]=1 -> edges int64.
// ---------------------------------------------------------------------------
__global__ void init_detect_kernel(int* cnt0, int* cnt1, float* t0, float* t1,
                                   const void* x1, const void* ei1, int* flags) {
  if (blockIdx.x == gridDim.x - 1) {
    __shared__ int cnt_wild, cnt_oddnz;
    if (threadIdx.x == 0) { cnt_wild = 0; cnt_oddnz = 0; }
    __syncthreads();
    const ushort* xu = (const ushort*)x1;
    int wild = 0;
#pragma unroll
    for (int k = 0; k < 4; k++) {
      ushort u = xu[threadIdx.x * 4 + k];
      int ex = (u >> 7) & 0xFF;
      if (ex >= 0x90) wild++;
    }
    if (wild) atomicAdd(&cnt_wild, wild);
    const int* ii = (const int*)ei1;
    if (ii[threadIdx.x * 2 + 1] != 0) atomicAdd(&cnt_oddnz, 1);
    __syncthreads();
    if (threadIdx.x == 0) {
      flags[0] = (cnt_wild > 64) ? 1 : 0;
      flags[1] = (cnt_oddnz < 8) ? 1 : 0;
    }
    return;
  }
  int i = blockIdx.x * blockDim.x + threadIdx.x;
  if (i < N_NODES) { cnt0[i] = 0; cnt1[i] = 0; t0[i] = 0.f; t1[i] = 0.f; }
}

// ---------------------------------------------------------------------------
// Privatized dst-histogram + rank (r11): blocks own EDGE CHUNKS (not node
// ranges -- r4's mistake), LDS sub-histogram per 5000-node quarter, merge
// with CONTIGUOUS atomicAdd (line-coalesced: ~640KB traffic vs r10's 41MB of
// scattered atomic lines). Rank = merge-returned base + LDS-atomic local
// rank (pass 2). Reads raw edge input (int32/int64 branch) -- cvt_ei deleted.
// grid (NCHUNK*4, 2) x 1024.
// ---------------------------------------------------------------------------
__global__ __launch_bounds__(1024) void count_rank_kernel(
    const void* e0, const void* e1, int* cnt0, int* cnt1,
    int* rank0, int* rank1, const int* flags) {
  int b = blockIdx.y;
  const void* e = b ? e1 : e0;
  int* cnt = b ? cnt1 : cnt0;
  int* rank = b ? rank1 : rank0;
  int chunk = blockIdx.x >> 2;
  int lo = (blockIdx.x & 3) * NQ;
  int ebeg = chunk * (N_EDGES / NCHUNK);
  int eend = ebeg + (N_EDGES / NCHUNK);
  __shared__ int hist[NQ];
  __shared__ int base[NQ];
  for (int k = threadIdx.x; k < NQ; k += 1024) hist[k] = 0;
  __syncthreads();
  bool w64 = flags[1] != 0;
  const int* d32 = (const int*)e + N_EDGES;
  const long long* d64 = (const long long*)e + N_EDGES;
  for (int i = ebeg + threadIdx.x; i < eend; i += 1024) {
    int d = w64 ? (int)d64[i] : d32[i];
    unsigned q = (unsigned)(d - lo);
    if (q < NQ) atomicAdd(&hist[q], 1);
  }
  __syncthreads();
  for (int k = threadIdx.x; k < NQ; k += 1024) {
    base[k] = atomicAdd(&cnt[lo + k], hist[k]);   // coalesced merge
    hist[k] = 0;                                  // reuse as local rank ctr
  }
  __syncthreads();
  for (int i = ebeg + threadIdx.x; i < eend; i += 1024) {
    int d = w64 ? (int)d64[i] : d32[i];
    unsigned q = (unsigned)(d - lo);
    if (q < NQ) rank[i] = base[q] + atomicAdd(&hist[q], 1);
  }
}

// Exclusive scan -> CSR row_ptr, fused with dinv = rsqrt(cnt+1).
__global__ __launch_bounds__(1024) void scan_kernel(const int* cnt0, const int* cnt1,
                                                    int* rp0, int* rp1,
                                                    float* dinv0, float* dinv1) {
  const int* cnt = blockIdx.x ? cnt1 : cnt0;
  int* rp = blockIdx.x ? rp1 : rp0;
  float* dinv = blockIdx.x ? dinv1 : dinv0;
  __shared__ int sd[1024];
  int tid = threadIdx.x;
  int base = tid * 20;
  int pref[20];
  int run = 0;
#pragma unroll
  for (int k = 0; k < 20; k++) {
    int i = base + k;
    int c = (i < N_NODES) ? cnt[i] : 0;
    if (i < N_NODES) dinv[i] = rsqrtf((float)c + 1.0f);
    run += c;
    pref[k] = run;
  }
  sd[tid] = run;
  __syncthreads();
  for (int off = 1; off < 1024; off <<= 1) {
    int v = (tid >= off) ? sd[tid - off] : 0;
    __syncthreads();
    sd[tid] += v;
    __syncthreads();
  }
  int offset = sd[tid] - run;
  if (tid == 0) rp[0] = 0;
#pragma unroll
  for (int k = 0; k < 20; k++) {
    int i = base + k;
    if (i < N_NODES) rp[i + 1] = offset + pref[k];
  }
}

// ---------------------------------------------------------------------------
// fill (r11): role-split blocks. First 313 blocks/branch: eg scatter (packed
// 4B: low16=src, high16=bf16(coef)) using precomputed rank -- NO atomics.
// Last NCHUNK*4 blocks/branch: t[src] += dinv[dst] via LDS float privatized
// histogram + coalesced merge (replaces r10's 640K scattered fabric atomics).
// Reads raw edge input. grid (313 + NCHUNK*4, 2) x 1024.
// ---------------------------------------------------------------------------
__global__ __launch_bounds__(1024) void fill_kernel(
    const void* e0, const void* e1,
    const float* dinv0, const float* dinv1,
    const int* rp0, const int* rp1,
    const int* rank0, const int* rank1,
    unsigned int* eg0, unsigned int* eg1,
    float* t0, float* t1, const int* flags) {
  int b = blockIdx.y;
  const void* e = b ? e1 : e0;
  const float* dinv = b ? dinv1 : dinv0;
  bool w64 = flags[1] != 0;
  const int* s32 = (const int*)e;
  const int* d32 = (const int*)e + N_EDGES;
  const long long* s64 = (const long long*)e;
  const long long* d64 = (const long long*)e + N_EDGES;
  if (blockIdx.x < 313) {                 // eg-scatter role
    const int* rp = b ? rp1 : rp0;
    const int* rank = b ? rank1 : rank0;
    unsigned int* eg = b ? eg1 : eg0;
    int i = blockIdx.x * 1024 + threadIdx.x;
    if (i >= N_EDGES) return;
    int src = w64 ? (int)s64[i] : s32[i];
    int dst = w64 ? (int)d64[i] : d32[i];
    int slot = rp[dst] + rank[i];
    eg[slot] = (unsigned int)src | ((unsigned int)f2bf(dinv[src] * dinv[dst]) << 16);
    return;
  }
  // t-accumulation role (privatized)
  float* t = b ? t1 : t0;
  int r = blockIdx.x - 313;
  int chunk = r >> 2;
  int lo = (r & 3) * NQ;
  int ebeg = chunk * (N_EDGES / NCHUNK);
  int eend = ebeg + (N_EDGES / NCHUNK);
  __shared__ float tl[NQ];
  for (int k = threadIdx.x; k < NQ; k += 1024) tl[k] = 0.f;
  __syncthreads();
  for (int i = ebeg + threadIdx.x; i < eend; i += 1024) {
    int src = w64 ? (int)s64[i] : s32[i];
    unsigned q = (unsigned)(src - lo);
    if (q < NQ) {
      int dst = w64 ? (int)d64[i] : d32[i];
      atomicAdd(&tl[q], dinv[dst]);
    }
  }
  __syncthreads();
  for (int k = threadIdx.x; k < NQ; k += 1024)
    atomicAdd(&t[lo + k], tl[k]);         // coalesced merge
}

// C[M,256] = A[M,256] @ W[256,256], W read RAW [k][n] (cvt_w deleted):
// coalesced row-read + LDS transpose scatter; stride 42 ushorts (21 dwords)
// keeps the b16 scatter <=4-way banked. 128x64 tile, 4 waves x (2Mx4N).
// A read raw with wave-uniform fp32/bf16 branch when maybe_f32.
__global__ __launch_bounds__(256) void gemm_kernel(
    const void* __restrict__ A0, const void* __restrict__ A1,
    const void* __restrict__ W,
    ushort* __restrict__ C0, ushort* __restrict__ C1,
    int maybe_f32, const int* __restrict__ flags) {
  const void* A = blockIdx.z ? A1 : A0;
  ushort* C = blockIdx.z ? C1 : C0;
  bool wf32 = flags[0] != 0;
  bool af32 = maybe_f32 && wf32;
  int m0 = blockIdx.x * 128;
  int n0 = blockIdx.y * 64;
  __shared__ ushort As[128][42];
  __shared__ ushort Bs[64][42];
  int tid = threadIdx.x;
  int wave = tid >> 6, lane = tid & 63;
  int quad = lane >> 4, r16 = lane & 15;
  f32x4 acc[2][4];
#pragma unroll
  for (int m = 0; m < 2; m++)
#pragma unroll
    for (int n = 0; n < 4; n++) acc[m][n] = (f32x4){0.f, 0.f, 0.f, 0.f};
  int la_row = tid >> 1;          // 0..127
  int la_c0 = (tid & 1) * 16;     // 0 or 16
  int bk = tid >> 3;              // 0..31 (k row of W)
  int bn0 = (tid & 7) * 8;        // n octet
  for (int k0 = 0; k0 < 256; k0 += 32) {
    int gr = m0 + la_row;
    if (af32) {
      const float* Af = (const float*)A;
      float4 v0 = {0,0,0,0}, v1 = v0, v2 = v0, v3 = v0;
      if (gr < N_NODES) {
        const float* pA = Af + gr * 256 + k0 + la_c0;
        v0 = *(const float4*)pA;       v1 = *(const float4*)(pA + 4);
        v2 = *(const float4*)(pA + 8); v3 = *(const float4*)(pA + 12);
      }
      ushort* d = &As[la_row][la_c0];
      d[0] = f2bf(v0.x); d[1] = f2bf(v0.y); d[2]  = f2bf(v0.z); d[3]  = f2bf(v0.w);
      d[4] = f2bf(v1.x); d[5] = f2bf(v1.y); d[6]  = f2bf(v1.z); d[7]  = f2bf(v1.w);
      d[8] = f2bf(v2.x); d[9] = f2bf(v2.y); d[10] = f2bf(v2.z); d[11] = f2bf(v2.w);
      d[12] = f2bf(v3.x); d[13] = f2bf(v3.y); d[14] = f2bf(v3.z); d[15] = f2bf(v3.w);
    } else {
      const ushort* Ab = (const ushort*)A;
      int4 w0 = {0,0,0,0}, w1 = w0;
      if (gr < N_NODES) {
        const ushort* pA = Ab + gr * 256 + k0 + la_c0;
        w0 = *(const int4*)pA;
        w1 = *(const int4*)(pA + 8);
      }
      *(int4*)&As[la_row][la_c0] = w0;
      *(int4*)&As[la_row][la_c0 + 8] = w1;
    }
    ushort wtmp[8];
    if (wf32) {
      const float* Wf = (const float*)W + (k0 + bk) * 256 + n0 + bn0;
      float4 u0 = *(const float4*)Wf;
      float4 u1 = *(const float4*)(Wf + 4);
      wtmp[0] = f2bf(u0.x); wtmp[1] = f2bf(u0.y); wtmp[2] = f2bf(u0.z); wtmp[3] = f2bf(u0.w);
      wtmp[4] = f2bf(u1.x); wtmp[5] = f2bf(u1.y); wtmp[6] = f2bf(u1.z); wtmp[7] = f2bf(u1.w);
    } else {
      *(int4*)wtmp = *(const int4*)((const ushort*)W + (k0 + bk) * 256 + n0 + bn0);
    }
#pragma unroll
    for (int j = 0; j < 8; j++) Bs[bn0 + j][bk] = wtmp[j];   // transpose scatter
    __syncthreads();
    bf16x8 a0 = *(const bf16x8*)&As[wave * 32 + r16][quad * 8];
    bf16x8 a1 = *(const bf16x8*)&As[wave * 32 + 16 + r16][quad * 8];
    bf16x8 bb0 = *(const bf16x8*)&Bs[r16][quad * 8];
    bf16x8 bb1 = *(const bf16x8*)&Bs[16 + r16][quad * 8];
    bf16x8 bb2 = *(const bf16x8*)&Bs[32 + r16][quad * 8];
    bf16x8 bb3 = *(const bf16x8*)&Bs[48 + r16][quad * 8];
    acc[0][0] = __builtin_amdgcn_mfma_f32_16x16x32_bf16(a0, bb0, acc[0][0], 0, 0, 0);
    acc[0][1] = __builtin_amdgcn_mfma_f32_16x16x32_bf16(a0, bb1, acc[0][1], 0, 0, 0);
    acc[0][2] = __builtin_amdgcn_mfma_f32_16x16x32_bf16(a0, bb2, acc[0][2], 0, 0, 0);
    acc[0][3] = __builtin_amdgcn_mfma_f32_16x16x32_bf16(a0, bb3, acc[0][3], 0, 0, 0);
    acc[1][0] = __builtin_amdgcn_mfma_f32_16x16x32_bf16(a1, bb0, acc[1][0], 0, 0, 0);
    acc[1][1] = __builtin_amdgcn_mfma_f32_16x16x32_bf16(a1, bb1, acc[1][1], 0, 0, 0);
    acc[1][2] = __builtin_amdgcn_mfma_f32_16x16x32_bf16(a1, bb2, acc[1][2], 0, 0, 0);
    acc[1][3] = __builtin_amdgcn_mfma_f32_16x16x32_bf16(a1, bb3, acc[1][3], 0, 0, 0);
    __syncthreads();
  }
#pragma unroll
  for (int m = 0; m < 2; m++) {
    int grb = m0 + wave * 32 + m * 16 + quad * 4;
#pragma unroll
    for (int r = 0; r < 4; r++) {
      int gr = grb + r;
      if (gr < N_NODES) {
        ushort* cp = C + gr * 256 + n0 + r16;
        cp[0]  = f2bf(acc[m][0][r]);
        cp[16] = f2bf(acc[m][1][r]);
        cp[32] = f2bf(acc[m][2][r]);
        cp[48] = f2bf(acc[m][3][r]);
      }
    }
  }
}

// H[i] = relu( dinv_i^2*XW[i] + sum_e coef_e*XW[src_e] + bias ).
// Wave = 2 independent 32-lane halves, one node each; lane owns 8 features;
// x4 unroll + dual accumulators: 8 full rows (64 lines) in flight (r8
// post-mortem: line-level MLP >> cache-slice residency). Bias read RAW.
__global__ __launch_bounds__(256) void agg_kernel(
    const ushort* __restrict__ XW0, const ushort* __restrict__ XW1,
    const float* __restrict__ dinv0, const float* __restrict__ dinv1,
    const int* __restrict__ rp0, const int* __restrict__ rp1,
    const unsigned int* __restrict__ eg0, const unsigned int* __restrict__ eg1,
    const void* __restrict__ bias,
    ushort* __restrict__ H0, ushort* __restrict__ H1,
    const int* __restrict__ flags) {
  int b = blockIdx.y;
  const ushort* XW = b ? XW1 : XW0;
  const float* dinv = b ? dinv1 : dinv0;
  const int* rp = b ? rp1 : rp0;
  const unsigned int* eg = b ? eg1 : eg0;
  ushort* H = b ? H1 : H0;
  int wave = threadIdx.x >> 6, lane = threadIdx.x & 63;
  int half = lane >> 5;
  int fl = (lane & 31) * 8;
  int i = blockIdx.x * 8 + wave * 2 + half;   // 2500*8 = 20000 exact
  float di = dinv[i];
  float selfw = di * di;
  us8 v = *(const us8*)(XW + i * 256 + fl);
  float acc[8], acc2[8];
#pragma unroll
  for (int k = 0; k < 8; k++) { acc[k] = selfw * bf2f(v[k]); acc2[k] = 0.f; }
  int e = rp[i], eend = rp[i + 1];
  for (; e + 4 <= eend; e += 4) {
    unsigned int p0 = eg[e], p1 = eg[e + 1], p2 = eg[e + 2], p3 = eg[e + 3];
    us8 r0 = *(const us8*)(XW + (p0 & 0xFFFFu) * 256 + fl);
    us8 r1 = *(const us8*)(XW + (p1 & 0xFFFFu) * 256 + fl);
    us8 r2 = *(const us8*)(XW + (p2 & 0xFFFFu) * 256 + fl);
    us8 r3 = *(const us8*)(XW + (p3 & 0xFFFFu) * 256 + fl);
    float w0 = bf2f((ushort)(p0 >> 16)), w1 = bf2f((ushort)(p1 >> 16));
    float w2 = bf2f((ushort)(p2 >> 16)), w3 = bf2f((ushort)(p3 >> 16));
#pragma unroll
    for (int k = 0; k < 8; k++) {
      acc[k]  += w0 * bf2f(r0[k]);
      acc2[k] += w1 * bf2f(r1[k]);
      acc[k]  += w2 * bf2f(r2[k]);
      acc2[k] += w3 * bf2f(r3[k]);
    }
  }
  for (; e < eend; e++) {
    unsigned int pp = eg[e];
    us8 r = *(const us8*)(XW + (pp & 0xFFFFu) * 256 + fl);
    float w = bf2f((ushort)(pp >> 16));
#pragma unroll
    for (int k = 0; k < 8; k++) acc[k] += w * bf2f(r[k]);
  }
  float bv[8];
  if (flags[0]) {
    const float* bf = (const float*)bias + fl;
    float4 c0 = *(const float4*)bf;
    float4 c1 = *(const float4*)(bf + 4);
    bv[0] = c0.x; bv[1] = c0.y; bv[2] = c0.z; bv[3] = c0.w;
    bv[4] = c1.x; bv[5] = c1.y; bv[6] = c1.z; bv[7] = c1.w;
  } else {
    us8 bb = *(const us8*)((const ushort*)bias + fl);
#pragma unroll
    for (int k = 0; k < 8; k++) bv[k] = bf2f(bb[k]);
  }
  us8 o;
#pragma unroll
  for (int k = 0; k < 8; k++)
    o[k] = f2bf(fmaxf(acc[k] + acc2[k] + bv[k], 0.f));
  *(us8*)(H + i * 256 + fl) = o;
}

// Partial column sums: wave w of block handles rows j = (blk*4+w) + 256*k.
__global__ __launch_bounds__(256) void colsum_kernel(
    const ushort* __restrict__ H0, const ushort* __restrict__ H1,
    const float* __restrict__ dinv0, const float* __restrict__ dinv1,
    const float* __restrict__ t0, const float* __restrict__ t1,
    float* __restrict__ P) {
  int b = blockIdx.y;
  const ushort* H = b ? H1 : H0;
  const float* dinv = b ? dinv1 : dinv0;
  const float* t = b ? t1 : t0;
  int wave = threadIdx.x >> 6, lane = threadIdx.x & 63;
  int wid = blockIdx.x * 4 + wave;        // 0..255
  int f4 = lane * 4;
  float a0 = 0.f, a1 = 0.f, a2 = 0.f, a3 = 0.f;
  for (int j = wid; j < N_NODES; j += 256) {
    float dj = dinv[j];
    float c = dj * (t[j] + dj);
    ushort4 u = *(const ushort4*)(H + j * 256 + f4);
    a0 += c * bf2f(u.x); a1 += c * bf2f(u.y);
    a2 += c * bf2f(u.z); a3 += c * bf2f(u.w);
  }
  __shared__ float part[4][256];
  part[wave][f4 + 0] = a0; part[wave][f4 + 1] = a1;
  part[wave][f4 + 2] = a2; part[wave][f4 + 3] = a3;
  __syncthreads();
  int f = threadIdx.x;
  float ssum = part[0][f] + part[1][f] + part[2][f] + part[3][f];
  P[(b * 64 + blockIdx.x) * 256 + f] = ssum;
}

// s = reduce partials; pooled = ((s0+s1)@W3)/(2N)+b3 ; out = pooled@Wl + bl.
// All weights read RAW with uniform dtype branch.
__global__ __launch_bounds__(256) void final_kernel(
    const float* __restrict__ P,
    const void* __restrict__ W3, const void* __restrict__ b3,
    const void* __restrict__ Wl, const void* __restrict__ bl,
    void* __restrict__ out, const int* __restrict__ flags) {
  __shared__ float v[256];
  __shared__ float pooled[256];
  bool f32 = flags[0] != 0;
  int t = threadIdx.x;
  float acc0 = 0.f, acc1 = 0.f;
  for (int b = 0; b < 64; b++) {
    acc0 += P[b * 256 + t];
    acc1 += P[(64 + b) * 256 + t];
  }
  v[t] = acc0 + acc1;
  __syncthreads();
  float acc = 0.f;
  if (f32) {
    const float* W3f = (const float*)W3;
    for (int f = 0; f < 256; f++) acc += v[f] * W3f[f * 256 + t];
    pooled[t] = acc * (1.0f / (2.0f * N_NODES)) + ((const float*)b3)[t];
  } else {
    const ushort* W3b = (const ushort*)W3;
    for (int f = 0; f < 256; f++) acc += v[f] * bf2f(W3b[f * 256 + t]);
    pooled[t] = acc * (1.0f / (2.0f * N_NODES)) + bf2f(((const ushort*)b3)[t]);
  }
  __syncthreads();
  if (t < 5) {
    float o;
    if (f32) {
      o = ((const float*)bl)[t];
      for (int h = 0; h < 256; h++) o += pooled[h] * ((const float*)Wl)[h * 5 + t];
      ((float*)out)[t] = o;
    } else {
      o = bf2f(((const ushort*)bl)[t]);
      for (int h = 0; h < 256; h++) o += pooled[h] * bf2f(((const ushort*)Wl)[h * 5 + t]);
      ((ushort*)out)[t] = f2bf(o);
    }
  }
}

extern "C" void kernel_launch(void* const* d_in, const int* in_sizes, int n_in,
                              void* d_out, int out_size, void* d_ws, size_t ws_size,
                              hipStream_t stream) {
  const void* x1 = d_in[0];
  const void* ei1 = d_in[1];
  const void* x2 = d_in[2];
  const void* ei2 = d_in[3];
  const void* W1 = d_in[4];
  const void* b1 = d_in[5];
  const void* W2 = d_in[6];
  const void* b2 = d_in[7];
  const void* W3 = d_in[8];
  const void* b3 = d_in[9];
  const void* Wl = d_in[10];
  const void* bl = d_in[11];

  char* p = (char*)d_ws;
  auto alloc = [&](size_t bytes) {
    char* r = p;
    p += (bytes + 255) & ~size_t(255);
    return r;
  };
  int* flags   = (int*)alloc(256);
  float* dinv0 = (float*)alloc(N_NODES * 4);
  float* dinv1 = (float*)alloc(N_NODES * 4);
  float* t0    = (float*)alloc(N_NODES * 4);
  float* t1    = (float*)alloc(N_NODES * 4);
  int* cnt0    = (int*)alloc(N_NODES * 4);
  int* cnt1    = (int*)alloc(N_NODES * 4);
  int* rp0     = (int*)alloc((N_NODES + 1) * 4);
  int* rp1     = (int*)alloc((N_NODES + 1) * 4);
  unsigned int* eg0 = (unsigned int*)alloc((size_t)N_EDGES * 4);
  unsigned int* eg1 = (unsigned int*)alloc((size_t)N_EDGES * 4);
  float* Pp    = (float*)alloc(2 * 64 * 256 * 4);
  ushort* xw0  = (ushort*)alloc((size_t)N_NODES * HID * 2);
  ushort* xw1  = (ushort*)alloc((size_t)N_NODES * HID * 2);
  ushort* h0   = (ushort*)alloc((size_t)N_NODES * HID * 2);
  ushort* h1   = (ushort*)alloc((size_t)N_NODES * HID * 2);
  // rank aliases xw0 (rank dead after fill; xw0 first written by gemm1).
  int* rank0  = (int*)xw0;
  int* rank1  = rank0 + N_EDGES;

  // --- init+detect, privatized count+rank, scan, fill(eg + privatized t) ---
  init_detect_kernel<<<(N_NODES + 255) / 256 + 1, 256, 0, stream>>>(
      cnt0, cnt1, t0, t1, x1, ei1, flags);
  count_rank_kernel<<<dim3(NCHUNK * 4, 2), 1024, 0, stream>>>(
      ei1, ei2, cnt0, cnt1, rank0, rank1, flags);
  scan_kernel<<<2, 1024, 0, stream>>>(cnt0, cnt1, rp0, rp1, dinv0, dinv1);
  fill_kernel<<<dim3(313 + NCHUNK * 4, 2), 1024, 0, stream>>>(
      ei1, ei2, dinv0, dinv1, rp0, rp1, rank0, rank1, eg0, eg1, t0, t1, flags);

  // Layer 1: xw = x @ W1 (raw x, raw W1) ; h = relu(agg(xw) + b1)
  gemm_kernel<<<dim3(157, 4, 2), 256, 0, stream>>>(x1, x2, W1, xw0, xw1, 1, flags);
  agg_kernel<<<dim3(2500, 2), 256, 0, stream>>>(
      xw0, xw1, dinv0, dinv1, rp0, rp1, eg0, eg1, b1, h0, h1, flags);

  // Layer 2: xw = h @ W2 (raw W2) ; h = relu(agg(xw) + b2)
  gemm_kernel<<<dim3(157, 4, 2), 256, 0, stream>>>(h0, h1, W2, xw0, xw1, 0, flags);
  agg_kernel<<<dim3(2500, 2), 256, 0, stream>>>(
      xw0, xw1, dinv0, dinv1, rp0, rp1, eg0, eg1, b2, h0, h1, flags);

  // Layer 3 + pool collapsed: s = sum_j c_j h2_j ; out = ((s0+s1)W3/(2N)+b3)@Wl+bl
  colsum_kernel<<<dim3(64, 2), 256, 0, stream>>>(h0, h1, dinv0, dinv1, t0, t1, Pp);
  final_kernel<<<1, 256, 0, stream>>>(Pp, W3, b3, Wl, bl, d_out, flags);
}